// Round 22
// baseline (53.883 us; speedup 1.0000x reference)
//
#include <hip/hip_runtime.h>
#include <hip/hip_bf16.h>

// n=2,t=16 -> 32 frames; C=64; HW=4096; M=512; 32 groups (2 ch/group).
#define NFRAME 32
#define CCH 64
#define HW 4096
#define MSLOT 512

typedef __attribute__((ext_vector_type(8))) short s16x8;    // 8 bf16 MFMA A/B frag
typedef __attribute__((ext_vector_type(16))) float f32x16;  // 32x32 MFMA C/D frag
typedef __attribute__((ext_vector_type(4))) unsigned int u32x4;
typedef __attribute__((ext_vector_type(2))) unsigned int u32x2;
typedef unsigned short u16;
typedef unsigned int u32;

// f32 workspace offsets
#define WS_STATS 0          // 1024*2 f32
#define WS_OFF   2048       // 32*64 f32
#define WS_BF16  4096       // u16 region starts here (float offset)
// u16 offsets inside bf16 region
#define BW_KV    0                         // [16 mt][8 f][512]  f=0..3 KF ks, f=4..7 VF (mh*2+ct)
#define BW_WZF   65536                     // [2 ot][4 ks][64 l][8]   wz A-frags
#define BW_WFF   69632                     // [32 b][2 ot][4 ks][64 l][8] phi A-frags

// exp2-domain scale: 1/sqrt(64) * log2(e)
#define QSCALE 0.18033688011112042f

static __device__ __forceinline__ u16 f2b(float f) {
  __hip_bfloat16 h = __float2bfloat16(f);
  return *reinterpret_cast<u16*>(&h);
}
// bf16 pair pack via v_cvt_pk_bf16_f32 (lane-local pure VALU op; RNE; safe as
// non-volatile asm — r5's miscompile was CROSS-LANE asm, this is arithmetic).
static __device__ __forceinline__ u32 pack2(float a, float b) {
  u32 r;
  asm("v_cvt_pk_bf16_f32 %0, %1, %2" : "=v"(r) : "v"(a), "v"(b));
  return r;
}
static __device__ __forceinline__ f32x16 zero16() {
  f32x16 z;
#pragma unroll
  for (int r = 0; r < 16; ++r) z[r] = 0.f;
  return z;
}
// D-layout -> B-frag transpose (verified r6): input 16 f32 regs e[] holding
// D[row rmap(r,hi)][col l5]; output B-frags f0 (k=0..15), f1 (k=16..31),
// lane row = l5. cvt_pk packs + convergent permlane32_swap builtin.
static __device__ __forceinline__ void d2b(const float* e, s16x8& f0, s16x8& f1) {
#pragma unroll
  for (int mh = 0; mh < 2; ++mh) {
    const u32 P0 = pack2(e[mh * 8 + 0], e[mh * 8 + 1]);
    const u32 P1 = pack2(e[mh * 8 + 2], e[mh * 8 + 3]);
    const u32 Q0 = pack2(e[mh * 8 + 4], e[mh * 8 + 5]);
    const u32 Q1 = pack2(e[mh * 8 + 6], e[mh * 8 + 7]);
    const u32x2 s0 = __builtin_amdgcn_permlane32_swap(P0, Q0, false, false);
    const u32x2 s1 = __builtin_amdgcn_permlane32_swap(P1, Q1, false, false);
    u32x4 bw = {s0[0], s1[0], s0[1], s1[1]};
    if (mh == 0) f0 = __builtin_bit_cast(s16x8, bw);
    else         f1 = __builtin_bit_cast(s16x8, bw);
  }
}

// ---------------- kernel 1: GroupNorm stats (blocks 0..1023) + KV/wz frag tables (1024..1295) ----------------
__global__ __launch_bounds__(256) void k_pre(const float* __restrict__ x,
                                             const float* __restrict__ mb,
                                             const float* __restrict__ wz_w,
                                             float* __restrict__ ws) {
  if (blockIdx.x < 1024) {
    const int bg = blockIdx.x;
    const float4* xp = (const float4*)(x + (size_t)bg * 8192);
    const int t = threadIdx.x;
    float s = 0.f, s2 = 0.f;
#pragma unroll
    for (int i = 0; i < 8; ++i) {
      float4 v = xp[t + i * 256];
      s  += v.x + v.y + v.z + v.w;
      s2 += v.x * v.x + v.y * v.y + v.z * v.z + v.w * v.w;
    }
    for (int off = 32; off; off >>= 1) {
      s  += __shfl_down(s,  off, 64);
      s2 += __shfl_down(s2, off, 64);
    }
    __shared__ float ls[8];
    const int wid = t >> 6;
    if ((t & 63) == 0) { ls[wid * 2] = s; ls[wid * 2 + 1] = s2; }
    __syncthreads();
    if (t == 0) {
      float S = 0.f, S2 = 0.f;
#pragma unroll
      for (int w = 0; w < 4; ++w) { S += ls[w * 2]; S2 += ls[w * 2 + 1]; }
      float mean = S * (1.f / 8192.f);
      float var  = S2 * (1.f / 8192.f) - mean * mean;
      float rstd = rsqrtf(var + 1e-6f);
      ws[WS_STATS + bg * 2]     = mean;
      ws[WS_STATS + bg * 2 + 1] = rstd;
    }
    return;
  }
  // fragment tables
  u16* wbw = (u16*)(ws + WS_BF16);
  const int i = (blockIdx.x - 1024) * 256 + threadIdx.x;
  if (i < 65536) {
    // KV[mt][f][l][j]: f<4 -> KF ks=f: c=f*16+(l>>5)*8+j, m=mt*32+(l&31)
    //                  f>=4 -> VF idx=f-4 (mh=idx>>1, ct=idx&1):
    //                          c=(idx&1)*32+(l&31), m=mt*32+(idx>>1)*16+(l>>5)*8+j
    const int j = i & 7, l = (i >> 3) & 63, f = (i >> 9) & 7, mt = i >> 12;
    float v;
    if (f < 4) {
      const int c = f * 16 + ((l >> 5) << 3) + j;
      const int m = mt * 32 + (l & 31);
      v = mb[c * MSLOT + m];
    } else {
      const int idx = f - 4;
      const int c = (idx & 1) * 32 + (l & 31);
      const int m = mt * 32 + (idx >> 1) * 16 + ((l >> 5) << 3) + j;
      v = mb[c * MSLOT + m];
    }
    wbw[BW_KV + i] = f2b(v);
  } else {                                   // WZF[ot][ks][l][j]: o=ot*32+(l&31), c=ks*16+(l>>5)*8+j
    const int i3 = i - 65536;
    const int j = i3 & 7, l = (i3 >> 3) & 63, ks = (i3 >> 9) & 3, ot = i3 >> 11;
    const int o = ot * 32 + (l & 31);
    const int c = ks * 16 + ((l >> 5) << 3) + j;
    wbw[BW_WZF + i3] = f2b(wz_w[o * 64 + c]);
  }
}

// ---------------- kernel 2: fold GN + scale into bf16 phi weights, emit frag-ordered WFF ----------------
__global__ __launch_bounds__(256) void k_prep(const float* __restrict__ phi_w,
                                              const float* __restrict__ phi_b,
                                              const float* __restrict__ gamma,
                                              const float* __restrict__ beta,
                                              float* __restrict__ ws) {
  const int b = blockIdx.x;
  const int o = threadIdx.x & 63;
  const int quad = threadIdx.x >> 6;
  __shared__ u16 wrow[64 * 64];
  __shared__ float offp[256];
  float offacc = 0.f;
#pragma unroll
  for (int ci = 0; ci < 16; ++ci) {
    const int c = quad * 16 + ci;
    const int g = c >> 1;
    const float mean = ws[WS_STATS + (b * 32 + g) * 2];
    const float rstd = ws[WS_STATS + (b * 32 + g) * 2 + 1];
    const float a = gamma[c] * rstd;
    const float d = beta[c] - mean * a;
    const float wv = phi_w[o * 64 + c];
    wrow[o * 64 + c] = f2b(wv * a * QSCALE);
    offacc += wv * d;
  }
  offp[threadIdx.x] = offacc;
  __syncthreads();
  if (quad == 0) {
    const float off = offp[o] + offp[64 + o] + offp[128 + o] + offp[192 + o];
    ws[WS_OFF + b * 64 + o] = (off + phi_b[o]) * QSCALE;
  }
  u16* wff = (u16*)(ws + WS_BF16) + BW_WFF + (size_t)b * 4096;
#pragma unroll
  for (int k = 0; k < 16; ++k) {
    const int il = threadIdx.x * 16 + k;      // [ot][ks][l][j]
    const int j = il & 7, l = (il >> 3) & 63, ks = (il >> 9) & 3, ot = il >> 11;
    const int oo = ot * 32 + (l & 31);
    const int c = ks * 16 + ((l >> 5) << 3) + j;
    wff[il] = wrow[oo * 64 + c];
  }
}

// ---------------- kernel 3: r19 structure + rolling 1-tile-ahead ds_read prefetch + tree ls ----------------
// r21 post-mortem: setprio null (no scheduler slack to arbitrate). Remaining
// in-loop latency terms: (1) head-of-iteration lgkm wait (~120+ cyc: 8
// ds_read_b128 issue -> QK stalls); (2) serial 15-add ls chain (~60 cyc, no
// fast-math reassociation). r22: rolling prefetch — read tile mt+1's frags
// into the ALTERNATE named set while tile mt computes; #pragma unroll 1 on
// the pair loop keeps 2 live bodies (r18's spill was 16 fully-inlined bodies
// + STAGE interleave, not this); pairwise tree-sum for ls (depth 4). Body
// otherwise r19-identical. Spill tripwire: WRITE_SIZE must stay 32768 KB.
__global__ __launch_bounds__(512, 4) void k_main(const float* __restrict__ x,
                                                 const float* __restrict__ ws,
                                                 const float* __restrict__ wz_b,
                                                 float* __restrict__ out) {
  const int b    = blockIdx.x >> 4;
  const int tile = blockIdx.x & 15;
  const int w    = threadIdx.x >> 6;          // 0..7
  const int lane = threadIdx.x & 63;
  const int l5 = lane & 31;
  const int hi = lane >> 5;
  const int p  = tile * 256 + w * 32 + l5;    // this lane's pixel column

  const u16* wb = (const u16*)(ws + WS_BF16);
  const float* xb = x + (size_t)b * CCH * HW;

  __shared__ __align__(16) u16 kv[8][8][512];   // 64KB: 8 staged K/V tiles

  // stage tile-half h (tiles h*8..h*8+7): wave w moves frag w of each tile (1KB each)
#define STAGEH(h_)                                                               \
  {                                                                              \
    _Pragma("unroll")                                                            \
    for (int r = 0; r < 8; ++r) {                                                \
      const u16* src = wb + BW_KV + ((size_t)(((h_) * 8 + r) * 8 + w)) * 512     \
                       + lane * 8;                                               \
      __builtin_amdgcn_global_load_lds(                                          \
          (const __attribute__((address_space(1))) void*)src,                    \
          (__attribute__((address_space(3))) void*)&kv[r][w][0], 16, 0, 0);      \
    }                                                                            \
  }

  // load tile t's 8 fragments from LDS into named sets
#define LOADT(t_, KF_, VF_)                                                      \
  {                                                                              \
    _Pragma("unroll")                                                            \
    for (int ks = 0; ks < 4; ++ks)                                               \
      KF_[ks] = *(const s16x8*)&kv[t_][ks][(size_t)lane * 8];                    \
    _Pragma("unroll")                                                            \
    for (int i = 0; i < 4; ++i)                                                  \
      VF_[i] = *(const s16x8*)&kv[t_][4 + i][(size_t)lane * 8];                  \
  }

  // compute one tile from a named set; tree-summed ls (all-positive, depth 4)
#define COMPUTE(KF_, VF_)                                                        \
  {                                                                              \
    f32x16 s = zero16();                                                         \
    _Pragma("unroll")                                                            \
    for (int ks = 0; ks < 4; ++ks)                                               \
      s = __builtin_amdgcn_mfma_f32_32x32x16_bf16(KF_[ks], q[ks], s, 0, 0, 0);   \
    float e[16];                                                                 \
    _Pragma("unroll")                                                            \
    for (int r = 0; r < 16; ++r) e[r] = exp2f(s[r]);                             \
    float t0 = (e[0] + e[1]) + (e[2] + e[3]);                                    \
    float t1 = (e[4] + e[5]) + (e[6] + e[7]);                                    \
    float t2 = (e[8] + e[9]) + (e[10] + e[11]);                                  \
    float t3 = (e[12] + e[13]) + (e[14] + e[15]);                                \
    Lacc += (t0 + t1) + (t2 + t3);                                               \
    s16x8 pf0, pf1;                                                              \
    d2b(e, pf0, pf1);                                                            \
    Y[0] = __builtin_amdgcn_mfma_f32_32x32x16_bf16(VF_[0], pf0, Y[0], 0, 0, 0);  \
    Y[1] = __builtin_amdgcn_mfma_f32_32x32x16_bf16(VF_[1], pf0, Y[1], 0, 0, 0);  \
    Y[0] = __builtin_amdgcn_mfma_f32_32x32x16_bf16(VF_[2], pf1, Y[0], 0, 0, 0);  \
    Y[1] = __builtin_amdgcn_mfma_f32_32x32x16_bf16(VF_[3], pf1, Y[1], 0, 0, 0);  \
  }

  STAGEH(0);   // tiles 0..7 fly under phase A

  // ---- phase A: x -> B-frags in-register; phi = Wfold @ x + off -> Q frags ----
  s16x8 q[4];
  {
    s16x8 bx[4];
#pragma unroll
    for (int ks = 0; ks < 4; ++ks) {
      const float* xc = xb + (size_t)(ks * 16 + hi * 8) * HW + p;
      float v[8];
#pragma unroll
      for (int j = 0; j < 8; ++j) v[j] = xc[(size_t)j * HW];
      u32x4 pk = {pack2(v[0], v[1]), pack2(v[2], v[3]),
                  pack2(v[4], v[5]), pack2(v[6], v[7])};
      bx[ks] = __builtin_bit_cast(s16x8, pk);
    }
    const float* offb = ws + WS_OFF + b * 64;
#pragma unroll
    for (int ot = 0; ot < 2; ++ot) {
      f32x16 acc = zero16();
#pragma unroll
      for (int ks = 0; ks < 4; ++ks) {
        const s16x8 a = *(const s16x8*)(wb + BW_WFF + ((((size_t)b * 2 + ot) * 4 + ks) * 64 + lane) * 8);
        acc = __builtin_amdgcn_mfma_f32_32x32x16_bf16(a, bx[ks], acc, 0, 0, 0);
      }
      float e[16];
#pragma unroll
      for (int rq = 0; rq < 4; ++rq) {
        const float4 offv = *(const float4*)(offb + ot * 32 + rq * 8 + hi * 4);
#pragma unroll
        for (int rr = 0; rr < 4; ++rr) e[rq * 4 + rr] = acc[rq * 4 + rr] + ((const float*)&offv)[rr];
      }
      d2b(e, q[ot * 2], q[ot * 2 + 1]);
    }
  }

  // ---- attention: full M=512 per wave; two barrier-free 8-tile stretches,
  // rolling 1-tile-ahead LDS->reg prefetch (named sets, unroll-1 pair loop) ----
  f32x16 Y[2];
#pragma unroll
  for (int ct = 0; ct < 2; ++ct) Y[ct] = zero16();
  float Lacc = 0.f;

  __syncthreads();   // half 0 staged (vmcnt drained by syncthreads semantics)

  {
    s16x8 kfA[4], vfA[4], kfB[4], vfB[4];
    LOADT(0, kfA, vfA);
#pragma unroll 1
    for (int mt2 = 0; mt2 < 4; ++mt2) {
      const int t0i = mt2 * 2;
      LOADT(t0i + 1, kfB, vfB);          // prefetch next while A computes
      COMPUTE(kfA, vfA);
      if (t0i + 2 < 8) LOADT(t0i + 2, kfA, vfA);
      COMPUTE(kfB, vfB);
    }
  }

  __syncthreads();   // all waves done reading half 0
  STAGEH(1);         // tiles 8..15 overwrite the buffer
  __syncthreads();   // half 1 staged

  {
    s16x8 kfA[4], vfA[4], kfB[4], vfB[4];
    LOADT(0, kfA, vfA);
#pragma unroll 1
    for (int mt2 = 0; mt2 < 4; ++mt2) {
      const int t0i = mt2 * 2;
      LOADT(t0i + 1, kfB, vfB);
      COMPUTE(kfA, vfA);
      if (t0i + 2 < 8) LOADT(t0i + 2, kfA, vfA);
      COMPUTE(kfB, vfB);
    }
  }

  const float Ltot = Lacc + __shfl_xor(Lacc, 32, 64);
  const float invL = 1.f / Ltot;

  // ---- Y -> wz B-frags (normalize + transpose in-register) ----
  s16x8 by[4];
#pragma unroll
  for (int ct = 0; ct < 2; ++ct) {
    float e[16];
#pragma unroll
    for (int r = 0; r < 16; ++r) e[r] = Y[ct][r] * invL;
    d2b(e, by[ct * 2], by[ct * 2 + 1]);
  }

  // ---- phase D: out = wz @ y + wz_b + x ----
  const float* xr = xb + p;
  float* ob = out + (size_t)b * CCH * HW + p;
#pragma unroll
  for (int ot = 0; ot < 2; ++ot) {
    f32x16 acc = zero16();
#pragma unroll
    for (int ks = 0; ks < 4; ++ks) {
      const s16x8 a = *(const s16x8*)(wb + BW_WZF + (((size_t)ot * 4 + ks) * 64 + lane) * 8);
      acc = __builtin_amdgcn_mfma_f32_32x32x16_bf16(a, by[ks], acc, 0, 0, 0);
    }
#pragma unroll
    for (int rq = 0; rq < 4; ++rq) {
      const int obase = ot * 32 + rq * 8 + hi * 4;
      const float4 bz = *(const float4*)(wz_b + obase);
#pragma unroll
      for (int rr = 0; rr < 4; ++rr) {
        const size_t idx = (size_t)(obase + rr) * HW;
        ob[idx] = acc[rq * 4 + rr] + ((const float*)&bz)[rr] + xr[idx];
      }
    }
  }
#undef COMPUTE
#undef LOADT
#undef STAGEH
}

extern "C" void kernel_launch(void* const* d_in, const int* in_sizes, int n_in,
                              void* d_out, int out_size, void* d_ws, size_t ws_size,
                              hipStream_t stream) {
  const float* x     = (const float*)d_in[0];
  const float* gamma = (const float*)d_in[1];
  const float* beta  = (const float*)d_in[2];
  const float* phi_w = (const float*)d_in[3];
  const float* phi_b = (const float*)d_in[4];
  const float* mb    = (const float*)d_in[5];
  const float* wz_w  = (const float*)d_in[6];
  const float* wz_b  = (const float*)d_in[7];
  float* out = (float*)d_out;
  float* ws  = (float*)d_ws;

  k_pre<<<1296, 256, 0, stream>>>(x, mb, wz_w, ws);
  k_prep<<<32, 256, 0, stream>>>(phi_w, phi_b, gamma, beta, ws);
  k_main<<<NFRAME * 16, 512, 0, stream>>>(x, ws, wz_b, out);
}

// Round 23
// 46.858 us; speedup vs baseline: 1.1499x; 1.1499x over previous
//
#include <hip/hip_runtime.h>
#include <hip/hip_bf16.h>

// n=2,t=16 -> 32 frames; C=64; HW=4096; M=512; 32 groups (2 ch/group).
#define NFRAME 32
#define CCH 64
#define HW 4096
#define MSLOT 512

typedef __attribute__((ext_vector_type(8))) short s16x8;    // 8 bf16 MFMA A/B frag
typedef __attribute__((ext_vector_type(16))) float f32x16;  // 32x32 MFMA C/D frag
typedef __attribute__((ext_vector_type(4))) unsigned int u32x4;
typedef __attribute__((ext_vector_type(2))) unsigned int u32x2;
typedef unsigned short u16;
typedef unsigned int u32;

// f32 workspace offsets
#define WS_STATS 0          // 1024*2 f32
#define WS_OFF   2048       // 32*64 f32
#define WS_BF16  4096       // u16 region starts here (float offset)
// u16 offsets inside bf16 region
#define BW_KV    0                         // [16 mt][8 f][512]  f=0..3 KF ks, f=4..7 VF (mh*2+ct)
#define BW_WZF   65536                     // [2 ot][4 ks][64 l][8]   wz A-frags
#define BW_WFF   69632                     // [32 b][2 ot][4 ks][64 l][8] phi A-frags

// exp2-domain scale: 1/sqrt(64) * log2(e)
#define QSCALE 0.18033688011112042f

static __device__ __forceinline__ u16 f2b(float f) {
  __hip_bfloat16 h = __float2bfloat16(f);
  return *reinterpret_cast<u16*>(&h);
}
// bf16 pair pack via v_cvt_pk_bf16_f32 (lane-local pure VALU op; RNE; safe as
// non-volatile asm — r5's miscompile was CROSS-LANE asm, this is arithmetic).
static __device__ __forceinline__ u32 pack2(float a, float b) {
  u32 r;
  asm("v_cvt_pk_bf16_f32 %0, %1, %2" : "=v"(r) : "v"(a), "v"(b));
  return r;
}
static __device__ __forceinline__ f32x16 zero16() {
  f32x16 z;
#pragma unroll
  for (int r = 0; r < 16; ++r) z[r] = 0.f;
  return z;
}
// D-layout -> B-frag transpose (verified r6): input 16 f32 regs e[] holding
// D[row rmap(r,hi)][col l5]; output B-frags f0 (k=0..15), f1 (k=16..31),
// lane row = l5. cvt_pk packs + convergent permlane32_swap builtin.
static __device__ __forceinline__ void d2b(const float* e, s16x8& f0, s16x8& f1) {
#pragma unroll
  for (int mh = 0; mh < 2; ++mh) {
    const u32 P0 = pack2(e[mh * 8 + 0], e[mh * 8 + 1]);
    const u32 P1 = pack2(e[mh * 8 + 2], e[mh * 8 + 3]);
    const u32 Q0 = pack2(e[mh * 8 + 4], e[mh * 8 + 5]);
    const u32 Q1 = pack2(e[mh * 8 + 6], e[mh * 8 + 7]);
    const u32x2 s0 = __builtin_amdgcn_permlane32_swap(P0, Q0, false, false);
    const u32x2 s1 = __builtin_amdgcn_permlane32_swap(P1, Q1, false, false);
    u32x4 bw = {s0[0], s1[0], s0[1], s1[1]};
    if (mh == 0) f0 = __builtin_bit_cast(s16x8, bw);
    else         f1 = __builtin_bit_cast(s16x8, bw);
  }
}

// ---------------- kernel 1: GroupNorm stats (blocks 0..1023) + KV/wz frag tables (1024..1295) ----------------
__global__ __launch_bounds__(256) void k_pre(const float* __restrict__ x,
                                             const float* __restrict__ mb,
                                             const float* __restrict__ wz_w,
                                             float* __restrict__ ws) {
  if (blockIdx.x < 1024) {
    const int bg = blockIdx.x;
    const float4* xp = (const float4*)(x + (size_t)bg * 8192);
    const int t = threadIdx.x;
    float s = 0.f, s2 = 0.f;
#pragma unroll
    for (int i = 0; i < 8; ++i) {
      float4 v = xp[t + i * 256];
      s  += v.x + v.y + v.z + v.w;
      s2 += v.x * v.x + v.y * v.y + v.z * v.z + v.w * v.w;
    }
    for (int off = 32; off; off >>= 1) {
      s  += __shfl_down(s,  off, 64);
      s2 += __shfl_down(s2, off, 64);
    }
    __shared__ float ls[8];
    const int wid = t >> 6;
    if ((t & 63) == 0) { ls[wid * 2] = s; ls[wid * 2 + 1] = s2; }
    __syncthreads();
    if (t == 0) {
      float S = 0.f, S2 = 0.f;
#pragma unroll
      for (int w = 0; w < 4; ++w) { S += ls[w * 2]; S2 += ls[w * 2 + 1]; }
      float mean = S * (1.f / 8192.f);
      float var  = S2 * (1.f / 8192.f) - mean * mean;
      float rstd = rsqrtf(var + 1e-6f);
      ws[WS_STATS + bg * 2]     = mean;
      ws[WS_STATS + bg * 2 + 1] = rstd;
    }
    return;
  }
  // fragment tables
  u16* wbw = (u16*)(ws + WS_BF16);
  const int i = (blockIdx.x - 1024) * 256 + threadIdx.x;
  if (i < 65536) {
    // KV[mt][f][l][j]: f<4 -> KF ks=f: c=f*16+(l>>5)*8+j, m=mt*32+(l&31)
    //                  f>=4 -> VF idx=f-4 (mh=idx>>1, ct=idx&1):
    //                          c=(idx&1)*32+(l&31), m=mt*32+(idx>>1)*16+(l>>5)*8+j
    const int j = i & 7, l = (i >> 3) & 63, f = (i >> 9) & 7, mt = i >> 12;
    float v;
    if (f < 4) {
      const int c = f * 16 + ((l >> 5) << 3) + j;
      const int m = mt * 32 + (l & 31);
      v = mb[c * MSLOT + m];
    } else {
      const int idx = f - 4;
      const int c = (idx & 1) * 32 + (l & 31);
      const int m = mt * 32 + (idx >> 1) * 16 + ((l >> 5) << 3) + j;
      v = mb[c * MSLOT + m];
    }
    wbw[BW_KV + i] = f2b(v);
  } else {                                   // WZF[ot][ks][l][j]: o=ot*32+(l&31), c=ks*16+(l>>5)*8+j
    const int i3 = i - 65536;
    const int j = i3 & 7, l = (i3 >> 3) & 63, ks = (i3 >> 9) & 3, ot = i3 >> 11;
    const int o = ot * 32 + (l & 31);
    const int c = ks * 16 + ((l >> 5) << 3) + j;
    wbw[BW_WZF + i3] = f2b(wz_w[o * 64 + c]);
  }
}

// ---------------- kernel 2: fold GN + scale into bf16 phi weights, emit frag-ordered WFF ----------------
__global__ __launch_bounds__(256) void k_prep(const float* __restrict__ phi_w,
                                              const float* __restrict__ phi_b,
                                              const float* __restrict__ gamma,
                                              const float* __restrict__ beta,
                                              float* __restrict__ ws) {
  const int b = blockIdx.x;
  const int o = threadIdx.x & 63;
  const int quad = threadIdx.x >> 6;
  __shared__ u16 wrow[64 * 64];
  __shared__ float offp[256];
  float offacc = 0.f;
#pragma unroll
  for (int ci = 0; ci < 16; ++ci) {
    const int c = quad * 16 + ci;
    const int g = c >> 1;
    const float mean = ws[WS_STATS + (b * 32 + g) * 2];
    const float rstd = ws[WS_STATS + (b * 32 + g) * 2 + 1];
    const float a = gamma[c] * rstd;
    const float d = beta[c] - mean * a;
    const float wv = phi_w[o * 64 + c];
    wrow[o * 64 + c] = f2b(wv * a * QSCALE);
    offacc += wv * d;
  }
  offp[threadIdx.x] = offacc;
  __syncthreads();
  if (quad == 0) {
    const float off = offp[o] + offp[64 + o] + offp[128 + o] + offp[192 + o];
    ws[WS_OFF + b * 64 + o] = (off + phi_b[o]) * QSCALE;
  }
  u16* wff = (u16*)(ws + WS_BF16) + BW_WFF + (size_t)b * 4096;
#pragma unroll
  for (int k = 0; k < 16; ++k) {
    const int il = threadIdx.x * 16 + k;      // [ot][ks][l][j]
    const int j = il & 7, l = (il >> 3) & 63, ks = (il >> 9) & 3, ot = il >> 11;
    const int oo = ot * 32 + (l & 31);
    const int c = ks * 16 + ((l >> 5) << 3) + j;
    wff[il] = wrow[oo * 64 + c];
  }
}

// ---------------- kernel 3: FINAL (r19, best measured 46.9us total) ----------------
// 8-wave 512-thr blocks; half of K/V (64KB) staged via global_load_lds, two
// barrier-free 8-tile stretches (3 barriers total; waves de-phase for cross-
// wave MFMA/VALU/LDS overlap per m114). 32 px/wave, 4 waves/SIMD (128-arch-
// VGPR cap — r11/r18/r22 all proved deeper register pipelining spills).
// Plateau evidence (r15-r22): sync variants, setprio, reg-prefetch, group
// staging, register residual all <=0 gain; issue-mix floor of this structure.
__global__ __launch_bounds__(512, 4) void k_main(const float* __restrict__ x,
                                                 const float* __restrict__ ws,
                                                 const float* __restrict__ wz_b,
                                                 float* __restrict__ out) {
  const int b    = blockIdx.x >> 4;
  const int tile = blockIdx.x & 15;
  const int w    = threadIdx.x >> 6;          // 0..7
  const int lane = threadIdx.x & 63;
  const int l5 = lane & 31;
  const int hi = lane >> 5;
  const int p  = tile * 256 + w * 32 + l5;    // this lane's pixel column

  const u16* wb = (const u16*)(ws + WS_BF16);
  const float* xb = x + (size_t)b * CCH * HW;

  __shared__ __align__(16) u16 kv[8][8][512];   // 64KB: 8 staged K/V tiles

  // stage tile-half h (tiles h*8..h*8+7): wave w moves frag w of each tile (1KB each)
#define STAGEH(h_)                                                               \
  {                                                                              \
    _Pragma("unroll")                                                            \
    for (int r = 0; r < 8; ++r) {                                                \
      const u16* src = wb + BW_KV + ((size_t)(((h_) * 8 + r) * 8 + w)) * 512     \
                       + lane * 8;                                               \
      __builtin_amdgcn_global_load_lds(                                          \
          (const __attribute__((address_space(1))) void*)src,                    \
          (__attribute__((address_space(3))) void*)&kv[r][w][0], 16, 0, 0);      \
    }                                                                            \
  }

  STAGEH(0);   // tiles 0..7 fly under phase A

  // ---- phase A: x -> B-frags in-register; phi = Wfold @ x + off -> Q frags ----
  s16x8 q[4];
  {
    s16x8 bx[4];
#pragma unroll
    for (int ks = 0; ks < 4; ++ks) {
      const float* xc = xb + (size_t)(ks * 16 + hi * 8) * HW + p;
      float v[8];
#pragma unroll
      for (int j = 0; j < 8; ++j) v[j] = xc[(size_t)j * HW];
      u32x4 pk = {pack2(v[0], v[1]), pack2(v[2], v[3]),
                  pack2(v[4], v[5]), pack2(v[6], v[7])};
      bx[ks] = __builtin_bit_cast(s16x8, pk);
    }
    const float* offb = ws + WS_OFF + b * 64;
#pragma unroll
    for (int ot = 0; ot < 2; ++ot) {
      f32x16 acc = zero16();
#pragma unroll
      for (int ks = 0; ks < 4; ++ks) {
        const s16x8 a = *(const s16x8*)(wb + BW_WFF + ((((size_t)b * 2 + ot) * 4 + ks) * 64 + lane) * 8);
        acc = __builtin_amdgcn_mfma_f32_32x32x16_bf16(a, bx[ks], acc, 0, 0, 0);
      }
      float e[16];
#pragma unroll
      for (int rq = 0; rq < 4; ++rq) {
        const float4 offv = *(const float4*)(offb + ot * 32 + rq * 8 + hi * 4);
#pragma unroll
        for (int rr = 0; rr < 4; ++rr) e[rq * 4 + rr] = acc[rq * 4 + rr] + ((const float*)&offv)[rr];
      }
      d2b(e, q[ot * 2], q[ot * 2 + 1]);
    }
  }

  // ---- attention: full M=512 per wave; two barrier-free 8-tile stretches ----
  f32x16 Y[2];
#pragma unroll
  for (int ct = 0; ct < 2; ++ct) Y[ct] = zero16();
  float Lacc = 0.f;

  __syncthreads();   // half 0 staged (vmcnt drained by syncthreads semantics)

#pragma unroll 2
  for (int mt = 0; mt < 8; ++mt) {
    s16x8 kf[4], vf[4];
#pragma unroll
    for (int ks = 0; ks < 4; ++ks)
      kf[ks] = *(const s16x8*)&kv[mt][ks][(size_t)lane * 8];
#pragma unroll
    for (int i = 0; i < 4; ++i)
      vf[i] = *(const s16x8*)&kv[mt][4 + i][(size_t)lane * 8];
    f32x16 s = zero16();
#pragma unroll
    for (int ks = 0; ks < 4; ++ks)
      s = __builtin_amdgcn_mfma_f32_32x32x16_bf16(kf[ks], q[ks], s, 0, 0, 0);
    float e[16];
    float ls = 0.f;
#pragma unroll
    for (int r = 0; r < 16; ++r) { e[r] = exp2f(s[r]); ls += e[r]; }
    Lacc += ls;
    s16x8 pf0, pf1;
    d2b(e, pf0, pf1);
    Y[0] = __builtin_amdgcn_mfma_f32_32x32x16_bf16(vf[0], pf0, Y[0], 0, 0, 0);
    Y[1] = __builtin_amdgcn_mfma_f32_32x32x16_bf16(vf[1], pf0, Y[1], 0, 0, 0);
    Y[0] = __builtin_amdgcn_mfma_f32_32x32x16_bf16(vf[2], pf1, Y[0], 0, 0, 0);
    Y[1] = __builtin_amdgcn_mfma_f32_32x32x16_bf16(vf[3], pf1, Y[1], 0, 0, 0);
  }

  __syncthreads();   // all waves done reading half 0
  STAGEH(1);         // tiles 8..15 overwrite the buffer
  __syncthreads();   // half 1 staged

#pragma unroll 2
  for (int mt = 0; mt < 8; ++mt) {
    s16x8 kf[4], vf[4];
#pragma unroll
    for (int ks = 0; ks < 4; ++ks)
      kf[ks] = *(const s16x8*)&kv[mt][ks][(size_t)lane * 8];
#pragma unroll
    for (int i = 0; i < 4; ++i)
      vf[i] = *(const s16x8*)&kv[mt][4 + i][(size_t)lane * 8];
    f32x16 s = zero16();
#pragma unroll
    for (int ks = 0; ks < 4; ++ks)
      s = __builtin_amdgcn_mfma_f32_32x32x16_bf16(kf[ks], q[ks], s, 0, 0, 0);
    float e[16];
    float ls = 0.f;
#pragma unroll
    for (int r = 0; r < 16; ++r) { e[r] = exp2f(s[r]); ls += e[r]; }
    Lacc += ls;
    s16x8 pf0, pf1;
    d2b(e, pf0, pf1);
    Y[0] = __builtin_amdgcn_mfma_f32_32x32x16_bf16(vf[0], pf0, Y[0], 0, 0, 0);
    Y[1] = __builtin_amdgcn_mfma_f32_32x32x16_bf16(vf[1], pf0, Y[1], 0, 0, 0);
    Y[0] = __builtin_amdgcn_mfma_f32_32x32x16_bf16(vf[2], pf1, Y[0], 0, 0, 0);
    Y[1] = __builtin_amdgcn_mfma_f32_32x32x16_bf16(vf[3], pf1, Y[1], 0, 0, 0);
  }

  const float Ltot = Lacc + __shfl_xor(Lacc, 32, 64);
  const float invL = 1.f / Ltot;

  // ---- Y -> wz B-frags (normalize + transpose in-register) ----
  s16x8 by[4];
#pragma unroll
  for (int ct = 0; ct < 2; ++ct) {
    float e[16];
#pragma unroll
    for (int r = 0; r < 16; ++r) e[r] = Y[ct][r] * invL;
    d2b(e, by[ct * 2], by[ct * 2 + 1]);
  }

  // ---- phase D: out = wz @ y + wz_b + x ----
  const float* xr = xb + p;
  float* ob = out + (size_t)b * CCH * HW + p;
#pragma unroll
  for (int ot = 0; ot < 2; ++ot) {
    f32x16 acc = zero16();
#pragma unroll
    for (int ks = 0; ks < 4; ++ks) {
      const s16x8 a = *(const s16x8*)(wb + BW_WZF + (((size_t)ot * 4 + ks) * 64 + lane) * 8);
      acc = __builtin_amdgcn_mfma_f32_32x32x16_bf16(a, by[ks], acc, 0, 0, 0);
    }
#pragma unroll
    for (int rq = 0; rq < 4; ++rq) {
      const int obase = ot * 32 + rq * 8 + hi * 4;
      const float4 bz = *(const float4*)(wz_b + obase);
#pragma unroll
      for (int rr = 0; rr < 4; ++rr) {
        const size_t idx = (size_t)(obase + rr) * HW;
        ob[idx] = acc[rq * 4 + rr] + ((const float*)&bz)[rr] + xr[idx];
      }
    }
  }
#undef STAGEH
}

extern "C" void kernel_launch(void* const* d_in, const int* in_sizes, int n_in,
                              void* d_out, int out_size, void* d_ws, size_t ws_size,
                              hipStream_t stream) {
  const float* x     = (const float*)d_in[0];
  const float* gamma = (const float*)d_in[1];
  const float* beta  = (const float*)d_in[2];
  const float* phi_w = (const float*)d_in[3];
  const float* phi_b = (const float*)d_in[4];
  const float* mb    = (const float*)d_in[5];
  const float* wz_w  = (const float*)d_in[6];
  const float* wz_b  = (const float*)d_in[7];
  float* out = (float*)d_out;
  float* ws  = (float*)d_ws;

  k_pre<<<1296, 256, 0, stream>>>(x, mb, wz_w, ws);
  k_prep<<<32, 256, 0, stream>>>(phi_w, phi_b, gamma, beta, ws);
  k_main<<<NFRAME * 16, 512, 0, stream>>>(x, ws, wz_b, out);
}